// Round 9
// baseline (240.739 us; speedup 1.0000x reference)
//
#include <hip/hip_runtime.h>
#include <hip/hip_bf16.h>

// JointNet: logp = log_softmax(tanh(enc@We + b_e (+) dec@Wd + b_d) @ Wfc + b_fc), masked.
// B=4 T=256 U=64 V=1024 F=1024 K_proj=512.
// R8 verdict: binder is the STAGING PATH (gload_lds + barriers + 1 block/CU lockstep),
// not panel bytes: 9-14 B/cy/CU constant across bf16/i8; m56 plain-load probe = 144 B/cy.
// R9: delete the machinery. B -> registers (plain global dwordx4, 4-slot pipeline,
// wave-private column slice, compiler-counted waits). A -> FULL 64KB i8 LDS tile built
// once in the prologue (tanh+quant). ZERO barriers in the K-loop. LDS 68KB -> 2 blocks/CU.

#define TT 256
#define UU 64
#define VV 1024
#define FF 1024
#define DK 512

typedef __bf16 bf16x8 __attribute__((ext_vector_type(8)));
typedef float  f32x16 __attribute__((ext_vector_type(16)));
typedef int    i32x4v __attribute__((ext_vector_type(4)));
typedef int    i32x16 __attribute__((ext_vector_type(16)));

__device__ __forceinline__ float fast_tanh(float x) {
  float ax = __builtin_fabsf(x);
  float e  = __expf(-2.0f * ax);
  float r  = (1.0f - e) * __builtin_amdgcn_rcpf(1.0f + e);
  return __builtin_copysignf(r, x);
}

// ---- pack enc/dec weights to bf16 frag-major [k8][1024][8]; quantize Wfc to i8 ----
// blocks 0..255: Wenc -> Pen ; 256..511: Wdec -> Pde ; 512..527: Wfc -> Pq + sc
__global__ __launch_bounds__(256)
void prep_w(const float* __restrict__ Wenc, const float* __restrict__ Wdec,
            const float* __restrict__ Wfc,
            __bf16* __restrict__ Pen, __bf16* __restrict__ Pde,
            signed char* __restrict__ Pq, float* __restrict__ sc)
{
  int bi = blockIdx.x;
  int tid = threadIdx.x;
  if (bi < 512) {
    const float* W = (bi < 256) ? Wenc : Wdec;
    __bf16* P = (bi < 256) ? Pen : Pde;
    int base = (bi < 256) ? bi : bi - 256;
    int idx = base * 256 + tid;          // idx = k8*1024 + v   (k8 < 64)
    int k8 = idx >> 10, v = idx & 1023;
    bf16x8 o;
#pragma unroll
    for (int j = 0; j < 8; ++j) o[j] = (__bf16)W[(k8 * 8 + j) * 1024 + v];
    *(bf16x8*)(P + (size_t)idx * 8) = o;
    return;
  }
  // ---- quantize W_fc: 16 blocks x 64 cols; 4 threads per col ----
  __shared__ float mx[4][64];
  __shared__ float smax[64];
  int blk = bi - 512;
  int p = tid >> 6;                      // 0..3
  int c = tid & 63;                      // 0..63
  int v = blk * 64 + c;
  float m = 0.f;
#pragma unroll 8
  for (int k = p * 256; k < p * 256 + 256; ++k)
    m = fmaxf(m, __builtin_fabsf(Wfc[k * 1024 + v]));
  mx[p][c] = m;
  __syncthreads();
  float mm = fmaxf(fmaxf(mx[0][c], mx[1][c]), fmaxf(mx[2][c], mx[3][c]));
  if (p == 0) { smax[c] = mm; sc[v] = (mm > 0.f) ? mm / 127.f : 1.f; }
  __syncthreads();
  float si = (smax[c] > 0.f) ? 127.f / smax[c] : 0.f;
  // phase2: thread p covers k16 in [p*16, p*16+16)
  for (int k16 = p * 16; k16 < p * 16 + 16; ++k16) {
    unsigned int w[4];
#pragma unroll
    for (int g = 0; g < 4; ++g) {
      unsigned int a = 0;
#pragma unroll
      for (int j = 0; j < 4; ++j) {
        float x = Wfc[(k16 * 16 + g * 4 + j) * 1024 + v];
        int q = (int)rintf(x * si);
        q = q > 127 ? 127 : (q < -127 ? -127 : q);
        a |= (unsigned int)(q & 255) << (8 * j);
      }
      w[g] = a;
    }
    *(uint4*)(Pq + ((size_t)k16 * 1024 + v) * 16) = make_uint4(w[0], w[1], w[2], w[3]);
  }
}

// ---------------- projections: pe = enc@We + be, pd = dec@Wd + bd (bf16 MFMA) ----
__global__ __launch_bounds__(256)
void proj_mfma(const float* __restrict__ enc, const float* __restrict__ dec,
               const __bf16* __restrict__ Pen, const __bf16* __restrict__ Pde,
               const float* __restrict__ be, const float* __restrict__ bd,
               float* __restrict__ pe, float* __restrict__ pd)
{
  constexpr int BK = 128;
  __shared__ __align__(16) char As[2][64 * BK * 2];   // 32KB
  const int tid = threadIdx.x;
  const int lane = tid & 63;
  const int wid  = tid >> 6;        // 0..3
  const int l31  = lane & 31;
  const int lhi  = lane >> 5;

  int bi = blockIdx.x;
  const float* X; const __bf16* PW; const float* bias; float* P; int rt, ct;
  if (bi < 64) { X = enc; PW = Pen; bias = be; P = pe; rt = bi >> 2; ct = bi & 3; }
  else { int bj = bi - 64; X = dec; PW = Pde; bias = bd; P = pd; rt = bj >> 2; ct = bj & 3; }
  const int r0 = rt * 64;

  auto fillA = [&](int buf, int kc) {
#pragma unroll
    for (int i = 0; i < 4; ++i) {
      int tau = i * 256 + tid;
      int r = tau >> 4, g = tau & 15;
      int k = kc * BK + g * 8;
      const float4* x4 = (const float4*)(X + (r0 + r) * DK + k);
      float4 a0 = x4[0], a1 = x4[1];
      float xv[8] = {a0.x, a0.y, a0.z, a0.w, a1.x, a1.y, a1.z, a1.w};
      bf16x8 p;
#pragma unroll
      for (int q = 0; q < 8; ++q) p[q] = (__bf16)xv[q];
      *(bf16x8*)(&As[buf][r * (BK * 2) + ((g * 16) ^ ((r & 7) << 4))]) = p;
    }
  };

  f32x16 acc[2][2];
#pragma unroll
  for (int mi = 0; mi < 2; ++mi)
#pragma unroll
    for (int ni = 0; ni < 2; ++ni)
#pragma unroll
      for (int q = 0; q < 16; ++q) acc[mi][ni][q] = 0.f;

  fillA(0, 0);
  __syncthreads();
  const int colBase = ct * 256 + wid * 64 + l31;
  for (int kc = 0; kc < DK / BK; ++kc) {
    if (kc + 1 < DK / BK) fillA((kc + 1) & 1, kc + 1);
    const char* Ab = As[kc & 1];
#pragma unroll 2
    for (int ks = 0; ks < BK / 16; ++ks) {
      int k8 = (kc * 8 + ks) * 2 + lhi;
      bf16x8 bfr[2];
#pragma unroll
      for (int ni = 0; ni < 2; ++ni)
        bfr[ni] = *(const bf16x8*)(PW + ((size_t)k8 * VV + colBase + ni * 32) * 8);
      bf16x8 afr[2];
#pragma unroll
      for (int mi = 0; mi < 2; ++mi) {
        int ra = mi * 32 + l31;
        int kb = ks * 32 + lhi * 16;
        afr[mi] = *(const bf16x8*)(&Ab[ra * (BK * 2) + (kb ^ ((ra & 7) << 4))]);
      }
#pragma unroll
      for (int mi = 0; mi < 2; ++mi)
#pragma unroll
        for (int ni = 0; ni < 2; ++ni)
          acc[mi][ni] = __builtin_amdgcn_mfma_f32_32x32x16_bf16(afr[mi], bfr[ni], acc[mi][ni], 0, 0, 0);
    }
    __syncthreads();
  }
  float bv[2];
#pragma unroll
  for (int ni = 0; ni < 2; ++ni) bv[ni] = bias[colBase + ni * 32];
#pragma unroll
  for (int mi = 0; mi < 2; ++mi)
#pragma unroll
    for (int j = 0; j < 16; ++j) {
      int row = r0 + mi * 32 + (j & 3) + 8 * (j >> 2) + 4 * lhi;
#pragma unroll
      for (int ni = 0; ni < 2; ++ni)
        P[row * VV + colBase + ni * 32] = acc[mi][ni][j] + bv[ni];
    }
}

// ---- main: per-(b,t) block; A fully pre-staged in LDS (64KB, one barrier);
// ---- B reg-pipelined (plain loads, wave-private cols); barrier-free K-loop.
__global__ __launch_bounds__(512, 2)
void joint_main(const float* __restrict__ pe, const float* __restrict__ pd,
                const signed char* __restrict__ Pq, const float* __restrict__ sc,
                const float* __restrict__ bfc,
                const int* __restrict__ elens, const int* __restrict__ dlens,
                float* __restrict__ out)
{
  // A: [k16 0..63][row 0..63] x 16B = 64KB (whole K range, staged once).
  __shared__ __align__(16) unsigned char Ab[65536];
  __shared__ float pr[8][64];
  __shared__ float lseS[64];

  const int blk = blockIdx.x;        // = b*T + t
  const int b = blk >> 8;
  const int t = blk & 255;
  const int tid = threadIdx.x;
  const int elen = elens[b], dlen = dlens[b];
  float* outBase = out + (size_t)blk * (UU * VV);

  if (t >= elen) {                   // whole 64x1024 tile masked -> zeros
    float4 z = {0.f, 0.f, 0.f, 0.f};
#pragma unroll 4
    for (int i = tid; i < UU * VV / 4; i += 512) ((float4*)outBase)[i] = z;
    return;
  }

  const int lane = tid & 63;
  const int wid  = tid >> 6;         // 0..7
  const int l31  = lane & 31;
  const int lhi  = lane >> 5;
  const int colLane = wid * 128 + l31;

  const float* peRow  = pe + (size_t)blk * FF;
  const float* pdBase = pd + (size_t)b * UU * FF;

  // ---- A prologue: full tile tanh(pe+pd) -> i8, one pass, one barrier ----
  {
    const int row = tid >> 3;                    // 0..63
    const float* pdRow = pdBase + (size_t)row * FF;
#pragma unroll
    for (int j = 0; j < 8; ++j) {
      int k16 = ((tid & 7) << 3) + j;            // 0..63
      const float4* e4 = (const float4*)(peRow + k16 * 16);
      const float4* d4 = (const float4*)(pdRow + k16 * 16);
      unsigned int w[4];
#pragma unroll
      for (int g = 0; g < 4; ++g) {
        float4 e = e4[g], d = d4[g];
        float h0 = e.x + d.x, h1 = e.y + d.y, h2 = e.z + d.z, h3 = e.w + d.w;
        unsigned int a = 0;
        a |= (unsigned int)(((int)rintf(fast_tanh(h0) * 127.f)) & 255);
        a |= (unsigned int)(((int)rintf(fast_tanh(h1) * 127.f)) & 255) << 8;
        a |= (unsigned int)(((int)rintf(fast_tanh(h2) * 127.f)) & 255) << 16;
        a |= (unsigned int)(((int)rintf(fast_tanh(h3) * 127.f)) & 255) << 24;
        w[g] = a;
      }
      *(uint4*)(&Ab[((k16 << 6) + row) << 4]) = make_uint4(w[0], w[1], w[2], w[3]);
    }
  }
  __syncthreads();                   // the ONLY barrier before the epilogue

  // ---- B register pipeline: 4 slots x 4 frags = 64 VGPRs, wave-private cols ----
  i32x4v bq[4][4];
  auto loadB = [&](int kc) {
    const signed char* gp = Pq + (size_t)kc * 32768;
#pragma unroll
    for (int ni = 0; ni < 4; ++ni)
      bq[kc & 3][ni] = *(const i32x4v*)(gp +
          ((size_t)((lhi << 10) + colLane + (ni << 5)) << 4));
  };

  i32x16 acc[2][4];
#pragma unroll
  for (int mi = 0; mi < 2; ++mi)
#pragma unroll
    for (int ni = 0; ni < 4; ++ni)
#pragma unroll
      for (int q = 0; q < 16; ++q) acc[mi][ni][q] = 0;

  loadB(0); loadB(1); loadB(2); loadB(3);

#pragma unroll
  for (int kc = 0; kc < 32; ++kc) {
    i32x4v afr[2];
#pragma unroll
    for (int mi = 0; mi < 2; ++mi)
      afr[mi] = *(const i32x4v*)(&Ab[((((kc << 1) + lhi) << 6) + mi * 32 + l31) << 4]);
#pragma unroll
    for (int mi = 0; mi < 2; ++mi)
#pragma unroll
      for (int ni = 0; ni < 4; ++ni)
        acc[mi][ni] = __builtin_amdgcn_mfma_i32_32x32x32_i8(afr[mi], bq[kc & 3][ni],
                                                            acc[mi][ni], 0, 0, 0);
    if (kc + 4 < 32) loadB(kc + 4);
  }

  // ---- epilogue: dequant + bias + exp row-sums (max-free; |logit| < 33) ----
  float bias[4], scl[4];
#pragma unroll
  for (int ni = 0; ni < 4; ++ni) {
    bias[ni] = bfc[colLane + ni * 32];
    scl[ni]  = sc[colLane + ni * 32] * (1.f / 127.f);
  }

  float rsum[2][16];
#pragma unroll
  for (int mi = 0; mi < 2; ++mi)
#pragma unroll
    for (int j = 0; j < 16; ++j) {
      float su = 0.f;
#pragma unroll
      for (int ni = 0; ni < 4; ++ni) {
        float v = (float)acc[mi][ni][j] * scl[ni] + bias[ni];
        acc[mi][ni][j] = __float_as_int(v);     // stash logit back in acc
        su += __expf(v);
      }
      rsum[mi][j] = su;
    }
#pragma unroll
  for (int st = 1; st < 32; st <<= 1) {
#pragma unroll
    for (int mi = 0; mi < 2; ++mi)
#pragma unroll
      for (int j = 0; j < 16; ++j)
        rsum[mi][j] += __shfl_xor(rsum[mi][j], st, 64);
  }
#pragma unroll
  for (int mi = 0; mi < 2; ++mi)
#pragma unroll
    for (int j = 0; j < 16; ++j)
      if (l31 == j) {
        int row = mi * 32 + (j & 3) + 8 * (j >> 2) + 4 * lhi;
        pr[wid][row] = rsum[mi][j];
      }
  __syncthreads();
  if (tid < 64) {
    float su = 0.f;
#pragma unroll
    for (int w = 0; w < 8; ++w) su += pr[w][tid];
    lseS[tid] = __logf(su);
  }
  __syncthreads();

#pragma unroll
  for (int mi = 0; mi < 2; ++mi)
#pragma unroll
    for (int j = 0; j < 16; ++j) {
      int row = mi * 32 + (j & 3) + 8 * (j >> 2) + 4 * lhi;
      float l = lseS[row];
      bool valid = row < dlen;
#pragma unroll
      for (int ni = 0; ni < 4; ++ni) {
        float v = valid ? (__int_as_float(acc[mi][ni][j]) - l) : 0.0f;
        outBase[(size_t)row * VV + colLane + ni * 32] = v;
      }
    }
}

extern "C" void kernel_launch(void* const* d_in, const int* in_sizes, int n_in,
                              void* d_out, int out_size, void* d_ws, size_t ws_size,
                              hipStream_t stream)
{
  const float* enc  = (const float*)d_in[0];
  const float* dec  = (const float*)d_in[1];
  const float* Wenc = (const float*)d_in[2];
  const float* benc = (const float*)d_in[3];
  const float* Wdec = (const float*)d_in[4];
  const float* bdec = (const float*)d_in[5];
  const float* Wfc  = (const float*)d_in[6];
  const float* bfc  = (const float*)d_in[7];
  const int* elens  = (const int*)d_in[8];
  const int* dlens  = (const int*)d_in[9];
  float* out = (float*)d_out;

  float* pe = (float*)d_ws;                       // 1024*1024 f32   (4 MB)
  float* pd = pe + 1024 * 1024;                   // 256*1024 f32    (1 MB)
  __bf16* Pen = (__bf16*)(pd + 256 * 1024);       // 512*1024 bf16   (1 MB)
  __bf16* Pde = Pen + 512 * 1024;                 // 512*1024 bf16   (1 MB)
  signed char* Pq = (signed char*)(Pde + 512 * 1024);  // 1024*1024 i8 (1 MB)
  float* sc = (float*)(Pq + 1024 * 1024);         // 1024 f32

  prep_w<<<528, 256, 0, stream>>>(Wenc, Wdec, Wfc, Pen, Pde, Pq, sc);
  proj_mfma<<<80, 256, 0, stream>>>(enc, dec, Pen, Pde, benc, bdec, pe, pd);
  joint_main<<<1024, 512, 0, stream>>>(pe, pd, Pq, sc, bfc, elens, dlens, out);
}